// Round 7
// baseline (186.773 us; speedup 1.0000x reference)
//
#include <hip/hip_runtime.h>
#include <hip/hip_bf16.h>

typedef __attribute__((ext_vector_type(8))) short bf16x8;
typedef __attribute__((ext_vector_type(4))) short bf16x4;
typedef __attribute__((ext_vector_type(4))) float f32x4;

#define NPEDS 65536
#define SEQ 12
#define HD 128
#define ED 64
#define MBLK 64
#define P1 136  // h-row pitch in elems (272 B, 16B-aligned rows)
#define WHH_FRAGS 128
#define WEFF_FRAGS 132  // 128 gate frags + 4 w_hp frags
#define NFRAGS (WHH_FRAGS + WEFF_FRAGS)
#define L2E 1.44269504088896340736f
#define NEG2L (-2.88539008177792681472f)
// float tail after frags: beff[512], b0eff[512], w2[1024]

__device__ __forceinline__ short f2bf(float x) {
  // RNE, compiles to v_cvt_pk_bf16_f32 (1 VALU op vs 4 for bit-twiddled)
  __hip_bfloat16 b = __float2bfloat16(x);
  return __builtin_bit_cast(short, b);
}
__device__ __forceinline__ float exp2_(float x) {
#if __has_builtin(__builtin_amdgcn_exp2f)
  return __builtin_amdgcn_exp2f(x);
#else
  return exp2f(x);
#endif
}

// Physical elem position of logical 4-elem k-group a=k>>2 within a row
// (fragment-contiguous layout): lane (llo,lhi), K-tile kt reads 8 contiguous
// elems at kt*32 + lhi*8, giving k = kt*32 + lhi*4 + (e&3) + (e>>2)*16.
__device__ __forceinline__ int pe_grp(int a) {
  return (a >> 3) * 32 + (a & 3) * 8 + ((a >> 2) & 1) * 4;
}

// Gate rows are PRE-SCALED by log2e (2*log2e for gate g, torch order i,f,g,o)
// so the kernel can use exp2 directly: sigm(x)=rcp(1+exp2(-y)), y=x*log2e;
// tanh(g)=(2-R)/R with R=1+exp2(-yg), yg=2*log2e*g.
// wsB layout (shorts):
//  [0, 128*512):         step-0 B frags (w_hh, scaled), frag = (cc*4+g)*4+kt
//  [128*512, 256*512):   W_eff gate frags (scaled),     frag = (cc*4+g)*4+kt
//  [256*512, 260*512):   w_hp rel frags (UNscaled),     frag = kt
//  float tail fl[]: fl[0:512) beff, fl[512:1024) b0eff, fl[1024:2048) w2[n][2]
//  (all three scaled)
__global__ void prep_kernel(const float* __restrict__ w_ih,
                            const float* __restrict__ w_hh,
                            const float* __restrict__ w_se,
                            const float* __restrict__ w_hp,
                            const float* __restrict__ b_ih,
                            const float* __restrict__ b_hh,
                            const float* __restrict__ b_se,
                            const float* __restrict__ b_hp,
                            short* __restrict__ wsB, float* __restrict__ fl) {
  int t = blockIdx.x * 256 + threadIdx.x;
  if (t < WHH_FRAGS * 64) {
    int frag = t >> 6, l = t & 63;
    int cc = frag >> 4, g = (frag >> 2) & 3, kt = frag & 3;
    float fac = (g == 2) ? 2.0f * L2E : L2E;
    int n = g * HD + cc * 16 + (l & 15);
    bf16x8 v;
#pragma unroll
    for (int e = 0; e < 8; ++e) {
      int k = kt * 32 + ((l >> 4) << 2) + (e & 3) + ((e >> 2) << 4);
      v[e] = f2bf(w_hh[n * HD + k] * fac);
    }
    *(bf16x8*)(wsB + (size_t)frag * 512 + l * 8) = v;
  } else if (t < NFRAGS * 64) {
    int u = t - WHH_FRAGS * 64;
    int frag = u >> 6, l = u & 63;
    int llo = l & 15;
    int ks[8];
#pragma unroll
    for (int e = 0; e < 8; ++e)
      ks[e] = (frag & 3) * 32 + ((l >> 4) << 2) + (e & 3) + ((e >> 2) << 4);
    float acc[8];
    if (frag < 128) {
      int cc = frag >> 4, g = (frag >> 2) & 3;
      float fac = (g == 2) ? 2.0f * L2E : L2E;
      int n = g * HD + cc * 16 + llo;
#pragma unroll
      for (int e = 0; e < 8; ++e) acc[e] = w_hh[n * HD + ks[e]];
      for (int j = 0; j < ED; ++j) {
        float wij = w_ih[n * ED + j];
        float se0 = w_se[2 * j], se1 = w_se[2 * j + 1];
#pragma unroll
        for (int e = 0; e < 8; ++e)
          acc[e] += wij * (se0 * w_hp[ks[e]] + se1 * w_hp[HD + ks[e]]);
      }
#pragma unroll
      for (int e = 0; e < 8; ++e) acc[e] *= fac;
    } else {
#pragma unroll
      for (int e = 0; e < 8; ++e)
        acc[e] = (llo < 2) ? w_hp[llo * HD + ks[e]] : 0.f;
    }
    bf16x8 v;
#pragma unroll
    for (int e = 0; e < 8; ++e) v[e] = f2bf(acc[e]);
    *(bf16x8*)(wsB + (size_t)(WHH_FRAGS + frag) * 512 + l * 8) = v;
  } else if (t < NFRAGS * 64 + 512) {
    int n = t - NFRAGS * 64;
    float fac = ((n >> 7) == 2) ? 2.0f * L2E : L2E;
    float b = b_ih[n] + b_hh[n];
    float s0 = 0.f, w20 = 0.f, w21 = 0.f;
    for (int j = 0; j < ED; ++j) {
      float wij = w_ih[n * ED + j];
      s0 += wij * b_se[j];
      w20 += wij * w_se[2 * j];
      w21 += wij * w_se[2 * j + 1];
    }
    fl[n] = fac * (b + s0 + w20 * b_hp[0] + w21 * b_hp[1]);  // beff (s>=1)
    fl[512 + n] = fac * (b + s0);                            // b0eff (step 0)
    fl[1024 + 2 * n] = fac * w20;  // w2 = w_ih @ w_se (scaled)
    fl[1024 + 2 * n + 1] = fac * w21;
  }
}

// launch_bounds(512, 4): 4 waves/EU -> combined (VGPR+AGPR) cap = 128/wave
// -> 2 resident 8-wave blocks per CU. Live set ~124 (Bw 64 + Af 16 + acc 16
// + creg 16 + misc) -- fits; beff moved to LDS to get under the cap.
__global__ __launch_bounds__(512, 4) void lstm_kernel(
    const float* __restrict__ lpr, const float* __restrict__ h0,
    const float* __restrict__ c0, const float* __restrict__ b_hp,
    const short* __restrict__ wsB, const float* __restrict__ fl,
    float* __restrict__ out) {
  __shared__ __align__(16) short hb[2][MBLK * P1];
  __shared__ __align__(16) short s_wsR[4 * 512];  // w_hp rel frags (4 KB)
  __shared__ float s_beff[512];                   // folded bias (steps >= 1)
  __shared__ float s_lpr[MBLK * 2];

  const int tid = threadIdx.x;
  const int cc = tid >> 6;  // wave id == 16-col chunk id (0..7)
  const int l = tid & 63;
  const int lhi = l >> 4;
  const int llo = l & 15;
  const int p0 = blockIdx.x * MBLK;
  const int hoff = (cc >> 1) * 32 + (llo >> 2) * 8 + (cc & 1) * 4 + (llo & 3);

  if (tid < 128) s_lpr[tid] = lpr[(size_t)p0 * 2 + tid];
  s_beff[tid] = fl[tid];
  // stage rel frags to LDS once (512 threads x 8 B = 4 KB)
  ((unsigned long long*)s_wsR)[tid] =
      ((const unsigned long long*)(wsB + (size_t)(WHH_FRAGS + 128) * 512))[tid];

  // B-fragments register file (16 frags, 64 VGPR). First filled with the
  // step-0 (w_hh) frags; swapped to W_eff after step 0.
  bf16x8 Bw[4][4];
#pragma unroll
  for (int g = 0; g < 4; ++g)
#pragma unroll
    for (int kt = 0; kt < 4; ++kt)
      Bw[g][kt] = *(const bf16x8*)(wsB +
                      (size_t)((cc * 4 + g) * 4 + kt) * 512 + l * 8);

  // c0 -> registers (C-tile layout, one 16-col chunk per wave, 4 M-tiles)
  float creg[4][4];
#pragma unroll
  for (int Mt = 0; Mt < 4; ++Mt)
#pragma unroll
    for (int r = 0; r < 4; ++r)
      creg[Mt][r] =
          c0[(size_t)(p0 + Mt * 16 + lhi * 4 + r) * HD + cc * 16 + llo];

  const float bhp_l = (llo < 2) ? b_hp[llo] : 0.f;

  // stage h0 -> hb[0] (pe layout): 2048 groups of 4 elems
#pragma unroll
  for (int i = 0; i < 4; ++i) {
    int grp = i * 512 + tid;
    int p = grp >> 5, a = grp & 31;
    f32x4 v = *(const f32x4*)(h0 + (size_t)(p0 + p) * HD + a * 4);
    bf16x4 s;
    s[0] = f2bf(v[0]); s[1] = f2bf(v[1]); s[2] = f2bf(v[2]); s[3] = f2bf(v[3]);
    *(bf16x4*)(&hb[0][p * P1 + pe_grp(a)]) = s;
  }
  __syncthreads();

  // 7-trans per-tile nonlinearity (gates pre-scaled by log2e / 2log2e):
  // cn = [c*Q*R + (2-R)*P] * rcp(P*Q*R);  hn = (2-T) * rcp(S*T)
  // cr passed as creg[Mt] at unrolled call sites -> static indexing.
  auto update_mt = [&](f32x4 (&acc)[4], float (&cr)[4], int rowb, short* An) {
#pragma unroll
    for (int r = 0; r < 4; ++r) {
      float yi = acc[0][r], yf = acc[1][r];
      float yg = acc[2][r], yo = acc[3][r];
      float P = 1.f + exp2_(-yf);
      float Q = 1.f + exp2_(-yi);
      float R = 1.f + exp2_(-yg);
      float QR = Q * R;
      float rD = __builtin_amdgcn_rcpf(P * QR);
      float cn = (cr[r] * QR + (2.f - R) * P) * rD;
      cr[r] = cn;
      float T = 1.f + exp2_(cn * NEG2L);
      float S = 1.f + exp2_(-yo);
      float hn = (2.f - T) * __builtin_amdgcn_rcpf(S * T);
      An[(rowb + r) * P1 + hoff] = f2bf(hn);
    }
  };

  // ---- step 0: gates = h0 @ w_hh.T + lpr @ w2.T + b0eff (rank-2 fold) ----
  {
    float b0r[4], w20r[4], w21r[4];
#pragma unroll
    for (int g = 0; g < 4; ++g) {
      int n = g * HD + cc * 16 + llo;
      b0r[g] = fl[512 + n];
      w20r[g] = fl[1024 + 2 * n];
      w21r[g] = fl[1024 + 2 * n + 1];
    }
#pragma unroll
    for (int Mt = 0; Mt < 4; ++Mt) {
      bf16x8 Af[4];
#pragma unroll
      for (int kt = 0; kt < 4; ++kt)
        Af[kt] =
            *(const bf16x8*)(&hb[0][(Mt * 16 + llo) * P1 + kt * 32 + lhi * 8]);
      f32x4 acc[4];
#pragma unroll
      for (int g = 0; g < 4; ++g)
#pragma unroll
        for (int r = 0; r < 4; ++r) {
          int row = Mt * 16 + lhi * 4 + r;
          acc[g][r] =
              b0r[g] + w20r[g] * s_lpr[row * 2] + w21r[g] * s_lpr[row * 2 + 1];
        }
#pragma unroll
      for (int kt = 0; kt < 4; ++kt)
#pragma unroll
        for (int g = 0; g < 4; ++g)
          acc[g] = __builtin_amdgcn_mfma_f32_16x16x32_bf16(Af[kt], Bw[g][kt],
                                                           acc[g], 0, 0, 0);
      update_mt(acc, creg[Mt], Mt * 16 + lhi * 4, hb[1]);
    }
    __syncthreads();
  }

  // swap Bw -> W_eff fragments (reused for all 11 recurrence steps)
  const short* wsW = wsB + (size_t)WHH_FRAGS * 512;
#pragma unroll
  for (int g = 0; g < 4; ++g)
#pragma unroll
    for (int kt = 0; kt < 4; ++kt)
      Bw[g][kt] = *(const bf16x8*)(wsW +
                      (size_t)((cc * 4 + g) * 4 + kt) * 512 + l * 8);

  // ---- steps 1..11: gates = h @ W_eff.T + beff, Mt-outer pipeline ----
  // Per M-tile: {Af reads -> 16 MFMA -> 4-elem trans update}; the trans
  // chain of tile Mt overlaps the MFMA/DS of tile Mt+1. Waves 4..7 fuse
  // their rel-MFMA (w_hp chunk) onto the already-loaded Af of tile cc-4.
  const int relMt = cc - 4;
  for (int s = 1; s < SEQ; ++s) {
    const short* A = hb[s & 1];
    short* An = hb[(s + 1) & 1];
    f32x4 ar = {bhp_l, bhp_l, bhp_l, bhp_l};
#pragma unroll
    for (int Mt = 0; Mt < 4; ++Mt) {
      bf16x8 Af[4];
#pragma unroll
      for (int kt = 0; kt < 4; ++kt)
        Af[kt] =
            *(const bf16x8*)(&A[(Mt * 16 + llo) * P1 + kt * 32 + lhi * 8]);
      f32x4 acc[4];
#pragma unroll
      for (int g = 0; g < 4; ++g) {
        float b = s_beff[g * HD + cc * 16 + llo];
        acc[g] = {b, b, b, b};
      }
#pragma unroll
      for (int kt = 0; kt < 4; ++kt)
#pragma unroll
        for (int g = 0; g < 4; ++g)
          acc[g] = __builtin_amdgcn_mfma_f32_16x16x32_bf16(Af[kt], Bw[g][kt],
                                                           acc[g], 0, 0, 0);
      if (cc >= 4 && Mt == relMt) {
#pragma unroll
        for (int kt = 0; kt < 4; ++kt) {
          bf16x8 BfR = *(const bf16x8*)(s_wsR + kt * 512 + l * 8);
          ar = __builtin_amdgcn_mfma_f32_16x16x32_bf16(Af[kt], BfR, ar, 0, 0,
                                                       0);
        }
      }
      update_mt(acc, creg[Mt], Mt * 16 + lhi * 4, An);
    }
    if (cc >= 4 && llo < 2) {
#pragma unroll
      for (int r = 0; r < 4; ++r)
        out[(size_t)(s - 1) * (NPEDS * 2) +
            (size_t)(p0 + relMt * 16 + lhi * 4 + r) * 2 + llo] = ar[r];
    }
    __syncthreads();
  }

  // ---- epilogue: rel(11) from h(12) in hb[SEQ & 1] ----
  if (cc >= 4) {
    const short* A = hb[SEQ & 1];
    f32x4 ar = {bhp_l, bhp_l, bhp_l, bhp_l};
#pragma unroll
    for (int kt = 0; kt < 4; ++kt) {
      bf16x8 BfR = *(const bf16x8*)(s_wsR + kt * 512 + l * 8);
      bf16x8 Afr =
          *(const bf16x8*)(&A[(relMt * 16 + llo) * P1 + kt * 32 + lhi * 8]);
      ar = __builtin_amdgcn_mfma_f32_16x16x32_bf16(Afr, BfR, ar, 0, 0, 0);
    }
    if (llo < 2) {
#pragma unroll
      for (int r = 0; r < 4; ++r)
        out[(size_t)(SEQ - 1) * (NPEDS * 2) +
            (size_t)(p0 + relMt * 16 + lhi * 4 + r) * 2 + llo] = ar[r];
    }
  }
}

extern "C" void kernel_launch(void* const* d_in, const int* in_sizes, int n_in,
                              void* d_out, int out_size, void* d_ws,
                              size_t ws_size, hipStream_t stream) {
  // setup_inputs order:
  // 0 last_pos (unused), 1 last_pos_rel, 2 h0, 3 c0, 4 w_ih, 5 w_hh,
  // 6 b_ih, 7 b_hh, 8 w_se, 9 b_se, 10 w_hp, 11 b_hp
  const float* lpr = (const float*)d_in[1];
  const float* h0 = (const float*)d_in[2];
  const float* c0 = (const float*)d_in[3];
  const float* w_ih = (const float*)d_in[4];
  const float* w_hh = (const float*)d_in[5];
  const float* b_ih = (const float*)d_in[6];
  const float* b_hh = (const float*)d_in[7];
  const float* w_se = (const float*)d_in[8];
  const float* b_se = (const float*)d_in[9];
  const float* w_hp = (const float*)d_in[10];
  const float* b_hp = (const float*)d_in[11];
  short* wsB = (short*)d_ws;  // frags 266240 B + float tail 8192 B = 274432 B
  float* fl = (float*)((char*)d_ws + (size_t)NFRAGS * 512 * sizeof(short));
  float* out = (float*)d_out;

  prep_kernel<<<67, 256, 0, stream>>>(w_ih, w_hh, w_se, w_hp, b_ih, b_hh,
                                      b_se, b_hp, wsB, fl);
  lstm_kernel<<<NPEDS / MBLK, 512, 0, stream>>>(lpr, h0, c0, b_hp, wsB, fl,
                                                out);
}

// Round 8
// 159.584 us; speedup vs baseline: 1.1704x; 1.1704x over previous
//
#include <hip/hip_runtime.h>
#include <hip/hip_bf16.h>

typedef __attribute__((ext_vector_type(8))) short bf16x8;
typedef __attribute__((ext_vector_type(4))) short bf16x4;
typedef __attribute__((ext_vector_type(4))) float f32x4;
typedef __attribute__((ext_vector_type(2))) float f32x2;

#define NPEDS 65536
#define SEQ 12
#define HD 128
#define ED 64
#define MBLK 128  // peds per block (8 ped-tiles of 16)
#define NPT 8
#define WHH_FRAGS 128
#define WEFF_FRAGS 132  // 128 gate frags + 4 w_hp frags
#define NFRAGS (WHH_FRAGS + WEFF_FRAGS)
#define L2E 1.44269504088896340736f
#define NEG2L (-2.88539008177792681472f)
// float tail after frags: beff[512], b0eff[512], w2[1024]

__device__ __forceinline__ short f2bf(float x) {
  __hip_bfloat16 b = __float2bfloat16(x);  // RNE, v_cvt bf16
  return __builtin_bit_cast(short, b);
}
__device__ __forceinline__ float exp2_(float x) {
#if __has_builtin(__builtin_amdgcn_exp2f)
  return __builtin_amdgcn_exp2f(x);
#else
  return exp2f(x);
#endif
}

// LDS h layout (shorts), swapped-operand B-fragment native:
// h[ped = Pt*16 + llo][col = colgrp*16 + lhi*4 + r] lives at
// hoff(Pt, colgrp, lhi, llo) + r  -> per-lane 8B units, conflict-free
// b64 writes (producer wave colgrp==cc) and b64 reads (consumer kt tiles).
__device__ __forceinline__ int hoff(int Pt, int cg, int lhi, int llo) {
  return (((Pt * 8 + cg) * 4 + lhi) * 16 + llo) * 4;
}

// Gate rows PRE-SCALED by log2e (2*log2e for gate g; torch order i,f,g,o):
// sigm(x)=rcp(1+exp2(-y)); tanh(g)=(2-R)/R, R=1+exp2(-yg).
// wsB layout (shorts) -- fragment (lane,elem) maps are identical for A and B
// operands of mfma 16x16x32, so this packing serves the swapped form too:
//  [0, 128*512):         step-0 frags (w_hh, scaled), frag = (cc*4+g)*4+kt
//  [128*512, 256*512):   W_eff gate frags (scaled),   frag = (cc*4+g)*4+kt
//  [256*512, 260*512):   w_hp rel frags (UNscaled),   frag = kt
//  float tail fl[]: fl[0:512) beff, fl[512:1024) b0eff, fl[1024:2048) w2[n][2]
__global__ void prep_kernel(const float* __restrict__ w_ih,
                            const float* __restrict__ w_hh,
                            const float* __restrict__ w_se,
                            const float* __restrict__ w_hp,
                            const float* __restrict__ b_ih,
                            const float* __restrict__ b_hh,
                            const float* __restrict__ b_se,
                            const float* __restrict__ b_hp,
                            short* __restrict__ wsB, float* __restrict__ fl) {
  int t = blockIdx.x * 256 + threadIdx.x;
  if (t < WHH_FRAGS * 64) {
    int frag = t >> 6, l = t & 63;
    int cc = frag >> 4, g = (frag >> 2) & 3, kt = frag & 3;
    float fac = (g == 2) ? 2.0f * L2E : L2E;
    int n = g * HD + cc * 16 + (l & 15);
    bf16x8 v;
#pragma unroll
    for (int e = 0; e < 8; ++e) {
      int k = kt * 32 + ((l >> 4) << 2) + (e & 3) + ((e >> 2) << 4);
      v[e] = f2bf(w_hh[n * HD + k] * fac);
    }
    *(bf16x8*)(wsB + (size_t)frag * 512 + l * 8) = v;
  } else if (t < NFRAGS * 64) {
    int u = t - WHH_FRAGS * 64;
    int frag = u >> 6, l = u & 63;
    int llo = l & 15;
    int ks[8];
#pragma unroll
    for (int e = 0; e < 8; ++e)
      ks[e] = (frag & 3) * 32 + ((l >> 4) << 2) + (e & 3) + ((e >> 2) << 4);
    float acc[8];
    if (frag < 128) {
      int cc = frag >> 4, g = (frag >> 2) & 3;
      float fac = (g == 2) ? 2.0f * L2E : L2E;
      int n = g * HD + cc * 16 + llo;
#pragma unroll
      for (int e = 0; e < 8; ++e) acc[e] = w_hh[n * HD + ks[e]];
      for (int j = 0; j < ED; ++j) {
        float wij = w_ih[n * ED + j];
        float se0 = w_se[2 * j], se1 = w_se[2 * j + 1];
#pragma unroll
        for (int e = 0; e < 8; ++e)
          acc[e] += wij * (se0 * w_hp[ks[e]] + se1 * w_hp[HD + ks[e]]);
      }
#pragma unroll
      for (int e = 0; e < 8; ++e) acc[e] *= fac;
    } else {
#pragma unroll
      for (int e = 0; e < 8; ++e)
        acc[e] = (llo < 2) ? w_hp[llo * HD + ks[e]] : 0.f;
    }
    bf16x8 v;
#pragma unroll
    for (int e = 0; e < 8; ++e) v[e] = f2bf(acc[e]);
    *(bf16x8*)(wsB + (size_t)(WHH_FRAGS + frag) * 512 + l * 8) = v;
  } else if (t < NFRAGS * 64 + 512) {
    int n = t - NFRAGS * 64;
    float fac = ((n >> 7) == 2) ? 2.0f * L2E : L2E;
    float b = b_ih[n] + b_hh[n];
    float s0 = 0.f, w20 = 0.f, w21 = 0.f;
    for (int j = 0; j < ED; ++j) {
      float wij = w_ih[n * ED + j];
      s0 += wij * b_se[j];
      w20 += wij * w_se[2 * j];
      w21 += wij * w_se[2 * j + 1];
    }
    fl[n] = fac * (b + s0 + w20 * b_hp[0] + w21 * b_hp[1]);  // beff (s>=1)
    fl[512 + n] = fac * (b + s0);                            // b0eff (step 0)
    fl[1024 + 2 * n] = fac * w20;  // w2 = w_ih @ w_se (scaled)
    fl[1024 + 2 * n + 1] = fac * w21;
  }
}

// Swapped-operand recurrence: gates^T = W_eff * h^T per 16x16 tile.
// W is the A-operand (persistent regs); h is the B-operand from LDS.
// C-layout: ped = llo, gatecol = lhi*4 + r  -> each lane holds all 4 gates
// of hidden unit n = cc*16 + lhi*4 + r for ped = Pt*16 + llo, and its 4
// produced h values are exactly the B-frag 8B this lane needs next step.
// launch_bounds(512,2): combined cap 256, live ~190 -- no spill (R7 lesson).
__global__ __launch_bounds__(512, 2) void lstm_kernel(
    const float* __restrict__ lpr, const float* __restrict__ h0,
    const float* __restrict__ c0, const float* __restrict__ b_hp,
    const short* __restrict__ wsB, const float* __restrict__ fl,
    float* __restrict__ out) {
  __shared__ short hb[2][NPT * 8 * 4 * 16 * 4];  // 2 x 32 KB, no pad needed

  const int tid = threadIdx.x;
  const int cc = tid >> 6;  // wave id == 16-hidden-col chunk (0..7)
  const int l = tid & 63;
  const int lhi = l >> 4;
  const int llo = l & 15;
  const int p0 = blockIdx.x * MBLK;

  // W fragments (A-operand), persistent: first w_hh (step 0), then W_eff
  bf16x8 Aw[4][4];
#pragma unroll
  for (int g = 0; g < 4; ++g)
#pragma unroll
    for (int kt = 0; kt < 4; ++kt)
      Aw[g][kt] = *(const bf16x8*)(wsB +
                      (size_t)((cc * 4 + g) * 4 + kt) * 512 + l * 8);
  // w_hp rel fragments (A-operand), persistent
  bf16x8 Whp[4];
#pragma unroll
  for (int kt = 0; kt < 4; ++kt)
    Whp[kt] = *(const bf16x8*)(wsB +
                  (size_t)(WHH_FRAGS + 128 + kt) * 512 + l * 8);

  // folded bias, vectorized over r: n = g*128 + cc*16 + lhi*4 + r
  f32x4 beffv[4];
#pragma unroll
  for (int g = 0; g < 4; ++g)
    beffv[g] = *(const f32x4*)&fl[g * HD + cc * 16 + lhi * 4];

  // c0 -> registers: lane (llo,lhi) ped = Pt*16+llo, units cc*16+lhi*4+r
  float creg[NPT][4];
#pragma unroll
  for (int Pt = 0; Pt < NPT; ++Pt) {
    f32x4 cv = *(const f32x4*)&c0[(size_t)(p0 + Pt * 16 + llo) * HD +
                                  cc * 16 + lhi * 4];
#pragma unroll
    for (int r = 0; r < 4; ++r) creg[Pt][r] = cv[r];
  }
  const float bhp0 = b_hp[0], bhp1 = b_hp[1];

  // stage h0 -> hb[0] in B-frag-native layout (b64 lanes, conflict-free)
#pragma unroll
  for (int i = 0; i < 8; ++i) {
    int idx = i * 512 + tid;  // 4096 items: ped x colgroup-of-4
    int a = idx & 31, ped = idx >> 5;
    f32x4 v = *(const f32x4*)&h0[(size_t)(p0 + ped) * HD + a * 4];
    bf16x4 sv;
    sv[0] = f2bf(v[0]); sv[1] = f2bf(v[1]);
    sv[2] = f2bf(v[2]); sv[3] = f2bf(v[3]);
    *(bf16x4*)&hb[0][hoff(ped >> 4, a >> 2, a & 3, ped & 15)] = sv;
  }
  __syncthreads();

  // 7-trans nonlinearity; writes this tile's h as ONE b64 (4 bf16)
  auto update_pt = [&](f32x4 (&acc)[4], float (&cr)[4], short* An, int Pt) {
    bf16x4 hn4;
#pragma unroll
    for (int r = 0; r < 4; ++r) {
      float yi = acc[0][r], yf = acc[1][r];
      float yg = acc[2][r], yo = acc[3][r];
      float P = 1.f + exp2_(-yf);
      float Q = 1.f + exp2_(-yi);
      float R = 1.f + exp2_(-yg);
      float QR = Q * R;
      float rD = __builtin_amdgcn_rcpf(P * QR);
      float cn = (cr[r] * QR + (2.f - R) * P) * rD;
      cr[r] = cn;
      float T = 1.f + exp2_(cn * NEG2L);
      float S = 1.f + exp2_(-yo);
      hn4[r] = f2bf((2.f - T) * __builtin_amdgcn_rcpf(S * T));
    }
    *(bf16x4*)&An[hoff(Pt, cc, lhi, llo)] = hn4;
  };

  // ---- step 0: gates^T = w_hh*h0^T + rank-2 lpr fold + b0eff ----
  {
    f32x4 b0v[4], wa[4], wb[4];
#pragma unroll
    for (int g = 0; g < 4; ++g) {
      int n0 = g * HD + cc * 16 + lhi * 4;
      b0v[g] = *(const f32x4*)&fl[512 + n0];
      wa[g] = *(const f32x4*)&fl[1024 + 2 * n0];      // w2[n0..n0+1][0:2]
      wb[g] = *(const f32x4*)&fl[1024 + 2 * n0 + 4];  // w2[n0+2..n0+3][0:2]
    }
#pragma unroll
    for (int Pt = 0; Pt < NPT; ++Pt) {
      f32x2 lp = *(const f32x2*)&lpr[(size_t)(p0 + Pt * 16 + llo) * 2];
      bf16x8 Bh[4];
#pragma unroll
      for (int kt = 0; kt < 4; ++kt) {
        bf16x4 lo = *(const bf16x4*)&hb[0][hoff(Pt, 2 * kt, lhi, llo)];
        bf16x4 hi = *(const bf16x4*)&hb[0][hoff(Pt, 2 * kt + 1, lhi, llo)];
        Bh[kt] = __builtin_shufflevector(lo, hi, 0, 1, 2, 3, 4, 5, 6, 7);
      }
      f32x4 acc[4];
#pragma unroll
      for (int g = 0; g < 4; ++g) {
        acc[g][0] = b0v[g][0] + wa[g][0] * lp[0] + wa[g][1] * lp[1];
        acc[g][1] = b0v[g][1] + wa[g][2] * lp[0] + wa[g][3] * lp[1];
        acc[g][2] = b0v[g][2] + wb[g][0] * lp[0] + wb[g][1] * lp[1];
        acc[g][3] = b0v[g][3] + wb[g][2] * lp[0] + wb[g][3] * lp[1];
      }
#pragma unroll
      for (int kt = 0; kt < 4; ++kt)
#pragma unroll
        for (int g = 0; g < 4; ++g)
          acc[g] = __builtin_amdgcn_mfma_f32_16x16x32_bf16(Aw[g][kt], Bh[kt],
                                                           acc[g], 0, 0, 0);
      update_pt(acc, creg[Pt], hb[1], Pt);
    }
    __syncthreads();
  }

  // swap Aw -> W_eff fragments for all 11 recurrence steps
  const short* wsW = wsB + (size_t)WHH_FRAGS * 512;
#pragma unroll
  for (int g = 0; g < 4; ++g)
#pragma unroll
    for (int kt = 0; kt < 4; ++kt)
      Aw[g][kt] = *(const bf16x8*)(wsW +
                      (size_t)((cc * 4 + g) * 4 + kt) * 512 + l * 8);

  // ---- steps 1..11: gates^T = W_eff*h^T + beff; wave cc fuses rel for
  // ped-tile Pt==cc on the B-frags already in registers ----
  for (int s = 1; s < SEQ; ++s) {
    const short* A = hb[s & 1];
    short* An = hb[(s + 1) & 1];
#pragma unroll
    for (int Pt = 0; Pt < NPT; ++Pt) {
      bf16x8 Bh[4];
#pragma unroll
      for (int kt = 0; kt < 4; ++kt) {
        bf16x4 lo = *(const bf16x4*)&A[hoff(Pt, 2 * kt, lhi, llo)];
        bf16x4 hi = *(const bf16x4*)&A[hoff(Pt, 2 * kt + 1, lhi, llo)];
        Bh[kt] = __builtin_shufflevector(lo, hi, 0, 1, 2, 3, 4, 5, 6, 7);
      }
      f32x4 acc[4];
#pragma unroll
      for (int g = 0; g < 4; ++g) acc[g] = beffv[g];
#pragma unroll
      for (int kt = 0; kt < 4; ++kt)
#pragma unroll
        for (int g = 0; g < 4; ++g)
          acc[g] = __builtin_amdgcn_mfma_f32_16x16x32_bf16(Aw[g][kt], Bh[kt],
                                                           acc[g], 0, 0, 0);
      if (Pt == cc) {  // rel(s-1) = h(s) @ w_hp^T + b_hp for this ped-tile
        f32x4 ar = {lhi == 0 ? bhp0 : 0.f, lhi == 0 ? bhp1 : 0.f, 0.f, 0.f};
#pragma unroll
        for (int kt = 0; kt < 4; ++kt)
          ar = __builtin_amdgcn_mfma_f32_16x16x32_bf16(Whp[kt], Bh[kt], ar, 0,
                                                       0, 0);
        if (lhi == 0) {
          f32x2 rv = {ar[0], ar[1]};
          *(f32x2*)&out[(size_t)(s - 1) * (NPEDS * 2) +
                        (size_t)(p0 + cc * 16 + llo) * 2] = rv;
        }
      }
      update_pt(acc, creg[Pt], An, Pt);
    }
    __syncthreads();
  }

  // ---- epilogue: rel(11) from h(12) in hb[SEQ & 1] == hb[0] ----
  {
    const short* A = hb[SEQ & 1];
    f32x4 ar = {lhi == 0 ? bhp0 : 0.f, lhi == 0 ? bhp1 : 0.f, 0.f, 0.f};
#pragma unroll
    for (int kt = 0; kt < 4; ++kt) {
      bf16x4 lo = *(const bf16x4*)&A[hoff(cc, 2 * kt, lhi, llo)];
      bf16x4 hi = *(const bf16x4*)&A[hoff(cc, 2 * kt + 1, lhi, llo)];
      bf16x8 Bh = __builtin_shufflevector(lo, hi, 0, 1, 2, 3, 4, 5, 6, 7);
      ar = __builtin_amdgcn_mfma_f32_16x16x32_bf16(Whp[kt], Bh, ar, 0, 0, 0);
    }
    if (lhi == 0) {
      f32x2 rv = {ar[0], ar[1]};
      *(f32x2*)&out[(size_t)(SEQ - 1) * (NPEDS * 2) +
                    (size_t)(p0 + cc * 16 + llo) * 2] = rv;
    }
  }
}

extern "C" void kernel_launch(void* const* d_in, const int* in_sizes, int n_in,
                              void* d_out, int out_size, void* d_ws,
                              size_t ws_size, hipStream_t stream) {
  // setup_inputs order:
  // 0 last_pos (unused), 1 last_pos_rel, 2 h0, 3 c0, 4 w_ih, 5 w_hh,
  // 6 b_ih, 7 b_hh, 8 w_se, 9 b_se, 10 w_hp, 11 b_hp
  const float* lpr = (const float*)d_in[1];
  const float* h0 = (const float*)d_in[2];
  const float* c0 = (const float*)d_in[3];
  const float* w_ih = (const float*)d_in[4];
  const float* w_hh = (const float*)d_in[5];
  const float* b_ih = (const float*)d_in[6];
  const float* b_hh = (const float*)d_in[7];
  const float* w_se = (const float*)d_in[8];
  const float* b_se = (const float*)d_in[9];
  const float* w_hp = (const float*)d_in[10];
  const float* b_hp = (const float*)d_in[11];
  short* wsB = (short*)d_ws;  // frags 266240 B + float tail 8192 B = 274432 B
  float* fl = (float*)((char*)d_ws + (size_t)NFRAGS * 512 * sizeof(short));
  float* out = (float*)d_out;

  prep_kernel<<<67, 256, 0, stream>>>(w_ih, w_hh, w_se, w_hp, b_ih, b_hh,
                                      b_se, b_hp, wsB, fl);
  lstm_kernel<<<NPEDS / MBLK, 512, 0, stream>>>(lpr, h0, c0, b_hp, wsB, fl,
                                                out);
}

// Round 9
// 157.282 us; speedup vs baseline: 1.1875x; 1.0146x over previous
//
#include <hip/hip_runtime.h>
#include <hip/hip_bf16.h>

typedef __attribute__((ext_vector_type(8))) short bf16x8;
typedef __attribute__((ext_vector_type(4))) short bf16x4;
typedef __attribute__((ext_vector_type(4))) float f32x4;
typedef __attribute__((ext_vector_type(2))) float f32x2;

#define NPEDS 65536
#define SEQ 12
#define HD 128
#define ED 64
#define MBLK 128  // peds per block (8 ped-tiles of 16)
#define NPT 8
#define WHH_FRAGS 128
#define WEFF_FRAGS 132  // 128 gate frags + 4 w_hp frags
#define NFRAGS (WHH_FRAGS + WEFF_FRAGS)
#define L2E 1.44269504088896340736f
#define NEG2L (-2.88539008177792681472f)
// float tail after frags: beff[512], b0eff[512], w2[1024]

__device__ __forceinline__ short f2bf(float x) {
  __hip_bfloat16 b = __float2bfloat16(x);  // RNE, v_cvt bf16
  return __builtin_bit_cast(short, b);
}
__device__ __forceinline__ float exp2_(float x) {
#if __has_builtin(__builtin_amdgcn_exp2f)
  return __builtin_amdgcn_exp2f(x);
#else
  return exp2f(x);
#endif
}

// LDS h layout (shorts), swapped-operand B-fragment native:
// h[ped = Pt*16 + llo][col = colgrp*16 + lhi*4 + r] lives at
// hoff(Pt, colgrp, lhi, llo) + r  -> per-lane 8B units, 2-way-free
// b64 writes (producer wave colgrp==cc) and b64 reads (consumer kt tiles).
__device__ __forceinline__ int hoff(int Pt, int cg, int lhi, int llo) {
  return (((Pt * 8 + cg) * 4 + lhi) * 16 + llo) * 4;
}

// Gate rows PRE-SCALED by log2e (2*log2e for gate g; torch order i,f,g,o):
// sigm(x)=rcp(1+exp2(-y)); tanh(g)=(2-R)/R, R=1+exp2(-yg).
// wsB layout (shorts) -- fragment (lane,elem) maps are identical for A and B
// operands of mfma 16x16x32, so this packing serves the swapped form too:
//  [0, 128*512):         step-0 frags (w_hh, scaled), frag = (cc*4+g)*4+kt
//  [128*512, 256*512):   W_eff gate frags (scaled),   frag = (cc*4+g)*4+kt
//  [256*512, 260*512):   w_hp rel frags (UNscaled),   frag = kt
//  float tail fl[]: fl[0:512) beff, fl[512:1024) b0eff, fl[1024:2048) w2[n][2]
__global__ void prep_kernel(const float* __restrict__ w_ih,
                            const float* __restrict__ w_hh,
                            const float* __restrict__ w_se,
                            const float* __restrict__ w_hp,
                            const float* __restrict__ b_ih,
                            const float* __restrict__ b_hh,
                            const float* __restrict__ b_se,
                            const float* __restrict__ b_hp,
                            short* __restrict__ wsB, float* __restrict__ fl) {
  int t = blockIdx.x * 256 + threadIdx.x;
  if (t < WHH_FRAGS * 64) {
    int frag = t >> 6, l = t & 63;
    int cc = frag >> 4, g = (frag >> 2) & 3, kt = frag & 3;
    float fac = (g == 2) ? 2.0f * L2E : L2E;
    int n = g * HD + cc * 16 + (l & 15);
    bf16x8 v;
#pragma unroll
    for (int e = 0; e < 8; ++e) {
      int k = kt * 32 + ((l >> 4) << 2) + (e & 3) + ((e >> 2) << 4);
      v[e] = f2bf(w_hh[n * HD + k] * fac);
    }
    *(bf16x8*)(wsB + (size_t)frag * 512 + l * 8) = v;
  } else if (t < NFRAGS * 64) {
    int u = t - WHH_FRAGS * 64;
    int frag = u >> 6, l = u & 63;
    int llo = l & 15;
    int ks[8];
#pragma unroll
    for (int e = 0; e < 8; ++e)
      ks[e] = (frag & 3) * 32 + ((l >> 4) << 2) + (e & 3) + ((e >> 2) << 4);
    float acc[8];
    if (frag < 128) {
      int cc = frag >> 4, g = (frag >> 2) & 3;
      float fac = (g == 2) ? 2.0f * L2E : L2E;
      int n = g * HD + cc * 16 + llo;
#pragma unroll
      for (int e = 0; e < 8; ++e) acc[e] = w_hh[n * HD + ks[e]];
      for (int j = 0; j < ED; ++j) {
        float wij = w_ih[n * ED + j];
        float se0 = w_se[2 * j], se1 = w_se[2 * j + 1];
#pragma unroll
        for (int e = 0; e < 8; ++e)
          acc[e] += wij * (se0 * w_hp[ks[e]] + se1 * w_hp[HD + ks[e]]);
      }
#pragma unroll
      for (int e = 0; e < 8; ++e) acc[e] *= fac;
    } else {
#pragma unroll
      for (int e = 0; e < 8; ++e)
        acc[e] = (llo < 2) ? w_hp[llo * HD + ks[e]] : 0.f;
    }
    bf16x8 v;
#pragma unroll
    for (int e = 0; e < 8; ++e) v[e] = f2bf(acc[e]);
    *(bf16x8*)(wsB + (size_t)(WHH_FRAGS + frag) * 512 + l * 8) = v;
  } else if (t < NFRAGS * 64 + 512) {
    int n = t - NFRAGS * 64;
    float fac = ((n >> 7) == 2) ? 2.0f * L2E : L2E;
    float b = b_ih[n] + b_hh[n];
    float s0 = 0.f, w20 = 0.f, w21 = 0.f;
    for (int j = 0; j < ED; ++j) {
      float wij = w_ih[n * ED + j];
      s0 += wij * b_se[j];
      w20 += wij * w_se[2 * j];
      w21 += wij * w_se[2 * j + 1];
    }
    fl[n] = fac * (b + s0 + w20 * b_hp[0] + w21 * b_hp[1]);  // beff (s>=1)
    fl[512 + n] = fac * (b + s0);                            // b0eff (step 0)
    fl[1024 + 2 * n] = fac * w20;  // w2 = w_ih @ w_se (scaled)
    fl[1024 + 2 * n + 1] = fac * w21;
  }
}

// Swapped-operand recurrence: gates^T = W_eff * h^T per 16x16 tile.
// W is the A-operand (persistent regs); h is the B-operand from LDS.
// C-layout: ped = llo, gatecol = lhi*4 + r.
// Steps loop uses a 2-stage ping-pong pipeline (named A/B sets, static
// indexing): tile Pt's MFMA chain is issued BEFORE tile Pt-1's trans-heavy
// nonlinearity, so the MFMA pipe and the VALU/trans pipe overlap within one
// wave (only 2 waves/SIMD resident -- cross-wave overlap is insufficient).
// launch_bounds(512,2): combined cap 256, live ~210 -- no spill.
__global__ __launch_bounds__(512, 2) void lstm_kernel(
    const float* __restrict__ lpr, const float* __restrict__ h0,
    const float* __restrict__ c0, const float* __restrict__ b_hp,
    const short* __restrict__ wsB, const float* __restrict__ fl,
    float* __restrict__ out) {
  __shared__ short hb[2][NPT * 8 * 4 * 16 * 4];  // 2 x 32 KB

  const int tid = threadIdx.x;
  const int cc = tid >> 6;  // wave id == 16-hidden-col chunk (0..7)
  const int l = tid & 63;
  const int lhi = l >> 4;
  const int llo = l & 15;
  const int p0 = blockIdx.x * MBLK;

  // W fragments (A-operand), persistent: first w_hh (step 0), then W_eff
  bf16x8 Aw[4][4];
#pragma unroll
  for (int g = 0; g < 4; ++g)
#pragma unroll
    for (int kt = 0; kt < 4; ++kt)
      Aw[g][kt] = *(const bf16x8*)(wsB +
                      (size_t)((cc * 4 + g) * 4 + kt) * 512 + l * 8);
  // w_hp rel fragments (A-operand), persistent
  bf16x8 Whp[4];
#pragma unroll
  for (int kt = 0; kt < 4; ++kt)
    Whp[kt] = *(const bf16x8*)(wsB +
                  (size_t)(WHH_FRAGS + 128 + kt) * 512 + l * 8);

  // folded bias as MFMA C-operand: n = g*128 + cc*16 + lhi*4 + r
  f32x4 beffv[4];
#pragma unroll
  for (int g = 0; g < 4; ++g)
    beffv[g] = *(const f32x4*)&fl[g * HD + cc * 16 + lhi * 4];

  // c0 -> registers: lane (llo,lhi) ped = Pt*16+llo, units cc*16+lhi*4+r
  float creg[NPT][4];
#pragma unroll
  for (int Pt = 0; Pt < NPT; ++Pt) {
    f32x4 cv = *(const f32x4*)&c0[(size_t)(p0 + Pt * 16 + llo) * HD +
                                  cc * 16 + lhi * 4];
#pragma unroll
    for (int r = 0; r < 4; ++r) creg[Pt][r] = cv[r];
  }
  const float bhp0 = b_hp[0], bhp1 = b_hp[1];

  // stage h0 -> hb[0] in B-frag-native layout (b64 lanes, conflict-free)
#pragma unroll
  for (int i = 0; i < 8; ++i) {
    int idx = i * 512 + tid;  // 4096 items: ped x colgroup-of-4
    int a = idx & 31, ped = idx >> 5;
    f32x4 v = *(const f32x4*)&h0[(size_t)(p0 + ped) * HD + a * 4];
    bf16x4 sv;
    sv[0] = f2bf(v[0]); sv[1] = f2bf(v[1]);
    sv[2] = f2bf(v[2]); sv[3] = f2bf(v[3]);
    *(bf16x4*)&hb[0][hoff(ped >> 4, a >> 2, a & 3, ped & 15)] = sv;
  }
  __syncthreads();

  // 7-trans nonlinearity; writes this tile's h as ONE b64 (4 bf16)
  auto update_pt = [&](f32x4 (&acc)[4], float (&cr)[4], short* An, int Pt) {
    bf16x4 hn4;
#pragma unroll
    for (int r = 0; r < 4; ++r) {
      float yi = acc[0][r], yf = acc[1][r];
      float yg = acc[2][r], yo = acc[3][r];
      float P = 1.f + exp2_(-yf);
      float Q = 1.f + exp2_(-yi);
      float R = 1.f + exp2_(-yg);
      float QR = Q * R;
      float rD = __builtin_amdgcn_rcpf(P * QR);
      float cn = (cr[r] * QR + (2.f - R) * P) * rD;
      cr[r] = cn;
      float T = 1.f + exp2_(cn * NEG2L);
      float S = 1.f + exp2_(-yo);
      hn4[r] = f2bf((2.f - T) * __builtin_amdgcn_rcpf(S * T));
    }
    *(bf16x4*)&An[hoff(Pt, cc, lhi, llo)] = hn4;
  };

  auto load_bh = [&](bf16x8 (&Bh)[4], const short* A, int Pt) {
#pragma unroll
    for (int kt = 0; kt < 4; ++kt) {
      bf16x4 lo = *(const bf16x4*)&A[hoff(Pt, 2 * kt, lhi, llo)];
      bf16x4 hi = *(const bf16x4*)&A[hoff(Pt, 2 * kt + 1, lhi, llo)];
      Bh[kt] = __builtin_shufflevector(lo, hi, 0, 1, 2, 3, 4, 5, 6, 7);
    }
  };
  // full gate MFMA chain; bias enters as the C operand of the first rank
  auto gates_mfma = [&](f32x4 (&acc)[4], bf16x8 (&Bh)[4]) {
    __builtin_amdgcn_s_setprio(1);
#pragma unroll
    for (int g = 0; g < 4; ++g)
      acc[g] = __builtin_amdgcn_mfma_f32_16x16x32_bf16(Aw[g][0], Bh[0],
                                                       beffv[g], 0, 0, 0);
#pragma unroll
    for (int kt = 1; kt < 4; ++kt)
#pragma unroll
      for (int g = 0; g < 4; ++g)
        acc[g] = __builtin_amdgcn_mfma_f32_16x16x32_bf16(Aw[g][kt], Bh[kt],
                                                         acc[g], 0, 0, 0);
    __builtin_amdgcn_s_setprio(0);
  };
  // rel(sout) = h @ w_hp^T + b_hp for this wave's ped-tile (Pt == cc)
  auto rel_do = [&](bf16x8 (&Bh)[4], int sout) {
    f32x4 ar = {lhi == 0 ? bhp0 : 0.f, lhi == 0 ? bhp1 : 0.f, 0.f, 0.f};
#pragma unroll
    for (int kt = 0; kt < 4; ++kt)
      ar = __builtin_amdgcn_mfma_f32_16x16x32_bf16(Whp[kt], Bh[kt], ar, 0, 0,
                                                   0);
    if (lhi == 0) {
      f32x2 rv = {ar[0], ar[1]};
      *(f32x2*)&out[(size_t)sout * (NPEDS * 2) +
                    (size_t)(p0 + cc * 16 + llo) * 2] = rv;
    }
  };

  // ---- step 0: gates^T = w_hh*h0^T + rank-2 lpr fold + b0eff ----
  {
    f32x4 b0v[4], wa[4], wb[4];
#pragma unroll
    for (int g = 0; g < 4; ++g) {
      int n0 = g * HD + cc * 16 + lhi * 4;
      b0v[g] = *(const f32x4*)&fl[512 + n0];
      wa[g] = *(const f32x4*)&fl[1024 + 2 * n0];      // w2[n0..n0+1][0:2]
      wb[g] = *(const f32x4*)&fl[1024 + 2 * n0 + 4];  // w2[n0+2..n0+3][0:2]
    }
#pragma unroll
    for (int Pt = 0; Pt < NPT; ++Pt) {
      f32x2 lp = *(const f32x2*)&lpr[(size_t)(p0 + Pt * 16 + llo) * 2];
      bf16x8 Bh[4];
      load_bh(Bh, hb[0], Pt);
      f32x4 acc[4];
#pragma unroll
      for (int g = 0; g < 4; ++g) {
        acc[g][0] = b0v[g][0] + wa[g][0] * lp[0] + wa[g][1] * lp[1];
        acc[g][1] = b0v[g][1] + wa[g][2] * lp[0] + wa[g][3] * lp[1];
        acc[g][2] = b0v[g][2] + wb[g][0] * lp[0] + wb[g][1] * lp[1];
        acc[g][3] = b0v[g][3] + wb[g][2] * lp[0] + wb[g][3] * lp[1];
      }
#pragma unroll
      for (int kt = 0; kt < 4; ++kt)
#pragma unroll
        for (int g = 0; g < 4; ++g)
          acc[g] = __builtin_amdgcn_mfma_f32_16x16x32_bf16(Aw[g][kt], Bh[kt],
                                                           acc[g], 0, 0, 0);
      update_pt(acc, creg[Pt], hb[1], Pt);
    }
    __syncthreads();
  }

  // swap Aw -> W_eff fragments for all 11 recurrence steps
  const short* wsW = wsB + (size_t)WHH_FRAGS * 512;
#pragma unroll
  for (int g = 0; g < 4; ++g)
#pragma unroll
    for (int kt = 0; kt < 4; ++kt)
      Aw[g][kt] = *(const bf16x8*)(wsW +
                      (size_t)((cc * 4 + g) * 4 + kt) * 512 + l * 8);

  // ---- steps 1..11: 2-stage ping-pong pipeline over ped-tiles ----
  for (int s = 1; s < SEQ; ++s) {
    const short* A = hb[s & 1];
    short* An = hb[(s + 1) & 1];
    bf16x8 BhA[4], BhB[4];
    f32x4 accA[4], accB[4];
    load_bh(BhA, A, 0);
    gates_mfma(accA, BhA);
#pragma unroll
    for (int Pt = 1; Pt < NPT; Pt += 2) {
      // stage B: issue next tile's loads + MFMA before finishing tile Pt-1
      load_bh(BhB, A, Pt);
      gates_mfma(accB, BhB);
      if (Pt - 1 == cc) rel_do(BhA, s - 1);
      update_pt(accA, creg[Pt - 1], An, Pt - 1);  // trans overlaps accB MFMA
      if (Pt + 1 < NPT) {
        load_bh(BhA, A, Pt + 1);
        gates_mfma(accA, BhA);
      }
      if (Pt == cc) rel_do(BhB, s - 1);
      update_pt(accB, creg[Pt], An, Pt);  // trans overlaps accA MFMA
    }
    __syncthreads();
  }

  // ---- epilogue: rel(11) from h(12) in hb[SEQ & 1] == hb[0] ----
  {
    bf16x8 Bh[4];
    load_bh(Bh, hb[SEQ & 1], cc);
    rel_do(Bh, SEQ - 1);
  }
}

extern "C" void kernel_launch(void* const* d_in, const int* in_sizes, int n_in,
                              void* d_out, int out_size, void* d_ws,
                              size_t ws_size, hipStream_t stream) {
  // setup_inputs order:
  // 0 last_pos (unused), 1 last_pos_rel, 2 h0, 3 c0, 4 w_ih, 5 w_hh,
  // 6 b_ih, 7 b_hh, 8 w_se, 9 b_se, 10 w_hp, 11 b_hp
  const float* lpr = (const float*)d_in[1];
  const float* h0 = (const float*)d_in[2];
  const float* c0 = (const float*)d_in[3];
  const float* w_ih = (const float*)d_in[4];
  const float* w_hh = (const float*)d_in[5];
  const float* b_ih = (const float*)d_in[6];
  const float* b_hh = (const float*)d_in[7];
  const float* w_se = (const float*)d_in[8];
  const float* b_se = (const float*)d_in[9];
  const float* w_hp = (const float*)d_in[10];
  const float* b_hp = (const float*)d_in[11];
  short* wsB = (short*)d_ws;  // frags 266240 B + float tail 8192 B = 274432 B
  float* fl = (float*)((char*)d_ws + (size_t)NFRAGS * 512 * sizeof(short));
  float* out = (float*)d_out;

  prep_kernel<<<67, 256, 0, stream>>>(w_ih, w_hh, w_se, w_hp, b_ih, b_hh,
                                      b_se, b_hp, wsB, fl);
  lstm_kernel<<<NPEDS / MBLK, 512, 0, stream>>>(lpr, h0, c0, b_hp, wsB, fl,
                                                out);
}